// Round 11
// baseline (619.058 us; speedup 1.0000x reference)
//
#include <hip/hip_runtime.h>

// RetinaNet 3D head via bf16 MFMA implicit GEMM.
// 2 heads x 4 levels (S=32,16,8,4; vox 32768,4096,512,64; total 37440).
//
// Layouts (r10-proven full-line loads + r11 tile change):
//   activations: [head][slice(8)][pvox][8ch]  (16B per (slice,vox))
//   weights:     [layer][head][tap][kg(4)][kb(2)][cout(64)][8ch]
// Conv wave tile: 32 vox x 64 cout (8 f32x4 accs). Block = 4 waves = 128 vox.
// Per tap per wave: 4 A-loads (distinct per wave) + 8 W-loads (1 voffset +
// imm 0..1792) -> 16 MFMAs.  MFMA:load = 1.33 (r10 was 0.67) and the 4x
// intra-block A redundancy is gone -> ~2x fewer load instrs per CU.
// Inline-asm loads, 2-tap ring, counted s_waitcnt vmcnt(12/0) +
// sched_barrier(0).  Strict producer->consumer dataflow (replay-safe).

typedef __attribute__((ext_vector_type(8)))  short short8;
typedef __attribute__((ext_vector_type(8)))  unsigned short ushort8;
typedef __attribute__((ext_vector_type(4)))  float f32x4;

static constexpr int TOTVOX    = 37440;
static constexpr int CLS_TOTAL = 673920;                  // 18 * 37440
static constexpr int TOTPADV   = 46352;                   // 39304+5832+1000+216
static constexpr size_t PAD_HSTRIDE_E = (size_t)TOTPADV * 64;  // elems per head
static constexpr size_t WLAYER_E = 2u * 27 * 4096;        // elems per layer (2 heads)

__device__ __forceinline__ unsigned short f2b(float x) {
    unsigned int u = __float_as_uint(x);
    u += 0x7FFFu + ((u >> 16) & 1u);
    return (unsigned short)(u >> 16);
}
__device__ __forceinline__ float b2f(unsigned short h) {
    return __uint_as_float(((unsigned)h) << 16);
}

// bijective XCD swizzles (m204 form)
__device__ __forceinline__ int xcdswz1170(int orig) {   // q=146, r=2
    const int xcd = orig & 7;
    return (xcd < 2 ? xcd * 147 : 294 + (xcd - 2) * 146) + (orig >> 3);
}
__device__ __forceinline__ int xcdswz293(int orig) {    // q=36, r=5
    const int xcd = orig & 7;
    return (xcd < 5 ? xcd * 37 : 185 + (xcd - 5) * 36) + (orig >> 3);
}

// 128-voxel conv blocks: b in [0,293): l0:256, l1:32, l2:4, l3:1
__device__ __forceinline__ void blkdec128(int b, int& lvl, int& ls, int& S, int& P,
                                          int& loff, int& cvol, int& base)
{
    if (b < 256)      { lvl = 0; base = b * 128; }
    else if (b < 288) { lvl = 1; base = 32768 + (b - 256) * 128; }
    else if (b < 292) { lvl = 2; base = 36864 + (b - 288) * 128; }
    else              { lvl = 3; base = 37376; }
    ls = 5 - lvl; S = 1 << ls; P = S + 2;
    loff = (lvl == 0) ? 0 : (lvl == 1) ? 32768 : (lvl == 2) ? 36864 : 37376;
    cvol = (lvl == 0) ? 0 : (lvl == 1) ? 39304 : (lvl == 2) ? 45136 : 46136;
}

// 32-voxel blocks (norm kernel): b in [0,1170)
__device__ __forceinline__ void blkdec32(int b, int& lvl, int& ls, int& S, int& P,
                                         int& loff, int& cvol, int& base)
{
    if (b < 1024)      { lvl = 0; base = b * 32; }
    else if (b < 1152) { lvl = 1; base = 32768 + (b - 1024) * 32; }
    else if (b < 1168) { lvl = 2; base = 36864 + (b - 1152) * 32; }
    else               { lvl = 3; base = 37376 + (b - 1168) * 32; }
    ls = 5 - lvl; S = 1 << ls; P = S + 2;
    loff = (lvl == 0) ? 0 : (lvl == 1) ? 32768 : (lvl == 2) ? 36864 : 37376;
    cvol = (lvl == 0) ? 0 : (lvl == 1) ? 39304 : (lvl == 2) ? 45136 : 46136;
}

__device__ __forceinline__ void voxdec(int vox, int& lvl, int& ls, int& loff,
                                       int& cvol, int& pbase)
{
    if (vox < 32768)      lvl = 0;
    else if (vox < 36864) lvl = 1;
    else if (vox < 37376) lvl = 2;
    else                  lvl = 3;
    ls = 5 - lvl;
    const int S = 1 << ls, P = S + 2;
    loff = (lvl == 0) ? 0 : (lvl == 1) ? 32768 : (lvl == 2) ? 36864 : 37376;
    cvol = (lvl == 0) ? 0 : (lvl == 1) ? 39304 : (lvl == 2) ? 45136 : 46136;
    const int v = vox - loff;
    const int x = v & (S - 1), y = (v >> ls) & (S - 1), z = v >> (2 * ls);
    pbase = ((z + 1) * P + (y + 1)) * P + (x + 1);
}

// ---------------------------------------------------------------------------
// Weight conversion -> bf16 [layer][head][tap][kg][kb][cout(64)][8ch].
// ---------------------------------------------------------------------------
__global__ __launch_bounds__(256) void wconv_kernel(
    const float* __restrict__ cls_w1, const float* __restrict__ reg_w1,
    const float* __restrict__ cls_w234, const float* __restrict__ reg_w234,
    const float* __restrict__ cls_wf, const float* __restrict__ reg_wf,
    unsigned short* __restrict__ dst)
{
    const int id = blockIdx.x * 256 + (int)threadIdx.x;   // < 1,105,920
    const int s  = id / 221184;
    const int r  = id - s * 221184;
    const int head = r / 110592;
    const int r2 = r - head * 110592;
    const int t  = r2 >> 12;
    const int q  = r2 & 4095;
    const int kgi = q >> 10;
    const int kb  = (q >> 9) & 1;
    const int co  = (q >> 3) & 63;
    const int ci  = (kb * 4 + kgi) * 8 + (q & 7);

    float val = 0.0f;
    if (s == 0) {
        if (ci < 36) {
            const float* w = head ? reg_w1 : cls_w1;      // [64][36][27]
            val = w[(co * 36 + ci) * 27 + t];
        }
    } else if (s <= 3) {
        const float* w = (head ? reg_w234 : cls_w234) + (size_t)(s - 1) * 110592;
        val = w[(co * 64 + ci) * 27 + t];                 // [64][64][27]
    } else {
        const int OUT = head ? 54 : 18;
        if (co < OUT) {
            const float* w = head ? reg_wf : cls_wf;      // [OUT][64][27]
            val = w[(co * 64 + ci) * 27 + t];
        }
    }
    dst[id] = f2b(val);
}

// ---------------------------------------------------------------------------
// Input conversion: p0..p3 fp32 [36][nvox] -> padded slice-major bf16.
// ---------------------------------------------------------------------------
__global__ __launch_bounds__(256) void inconv_kernel(
    const float* __restrict__ p0, const float* __restrict__ p1,
    const float* __restrict__ p2, const float* __restrict__ p3,
    unsigned short* __restrict__ padin)
{
    const int id = blockIdx.x * 256 + (int)threadIdx.x;   // < 299,520
    const int s   = id / 37440;
    const int vox = id - s * 37440;

    int lvl, ls, loff, cvol, pbase;
    voxdec(vox, lvl, ls, loff, cvol, pbase);
    const int nvox = 1 << (3 * ls);
    const int lvox = vox - loff;
    const float* src = (lvl == 0) ? p0 : (lvl == 1) ? p1 : (lvl == 2) ? p2 : p3;

    ushort8 o;
    #pragma unroll
    for (int j = 0; j < 8; ++j) {
        const int c = s * 8 + j;
        o[j] = (c < 36) ? f2b(src[c * nvox + lvox]) : (unsigned short)0;
    }
    *reinterpret_cast<ushort8*>(padin + ((size_t)s * TOTPADV + cvol + pbase) * 8) = o;
}

// ---------------------------------------------------------------------------
// Conv layer: implicit GEMM. Grid (293, 2 heads), 256 thr = 4 waves.
// Block tile: 128 vox x 64 cout ; wave: 32 vox x 64 cout (8 f32x4 accs).
// Per tap: 4 A-loads + 8 W-loads (asm, 2-tap ring, counted vmcnt); 16 MFMAs.
// ---------------------------------------------------------------------------
template<bool FINAL>
__global__ __launch_bounds__(256, 3) void conv_mfma_kernel(
    const unsigned short* __restrict__ A, const size_t a_head_stride_e,
    const unsigned short* __restrict__ W,
    const float* __restrict__ b_cls, const float* __restrict__ b_reg,
    float* __restrict__ stats, unsigned short* __restrict__ raw,
    float* __restrict__ dout)
{
    const int tid  = threadIdx.x;
    const int head = blockIdx.y;
    const int b    = xcdswz293(blockIdx.x);

    int lvl, ls, S, P, loff, cvol, base;
    blkdec128(b, lvl, ls, S, P, loff, cvol, base);

    const int lane = tid & 63, wv = tid >> 6;
    const int row = lane & 15, kg = lane >> 4;

    // wave voxel range (level 3 has only 64 vox: waves 2,3 mirror 0,1)
    const int wbase = base + ((lvl == 3) ? (wv & 1) : wv) * 32;
    const bool wvalid = !(lvl == 3 && wv >= 2);

    const unsigned short* Abase = A + (size_t)head * a_head_stride_e;
    const unsigned short* Wh = W + (size_t)head * (27 * 4096);

    unsigned avF0, avF1, wvoff;
    {
        const int v0 = (wbase - loff) + row;
        const int x0 = v0 & (S - 1), y0 = (v0 >> ls) & (S - 1), z0 = v0 >> (2 * ls);
        const int pb0 = ((z0 + 1) * P + (y0 + 1)) * P + (x0 + 1);
        const int v1 = v0 + 16;
        const int x1 = v1 & (S - 1), y1 = (v1 >> ls) & (S - 1), z1 = v1 >> (2 * ls);
        const int pb1 = ((z1 + 1) * P + (y1 + 1)) * P + (x1 + 1);
        avF0 = (unsigned)((kg * TOTPADV + cvol + pb0) * 16);
        avF1 = (unsigned)((kg * TOTPADV + cvol + pb1) * 16);
    }
    wvoff = (unsigned)(kg * 2048 + row * 16);

    f32x4 c[2][4];
    #pragma unroll
    for (int i = 0; i < 2; ++i)
        #pragma unroll
        for (int g = 0; g < 4; ++g) c[i][g] = f32x4{0.f, 0.f, 0.f, 0.f};

    // 2-slot ring, 12 short8 per slot
    short8 aA0_0,aA1_0,aB0_0,aB1_0,w00_0,w01_0,w02_0,w03_0,w10_0,w11_0,w12_0,w13_0;
    short8 aA0_1,aA1_1,aB0_1,aB1_1,w00_1,w01_1,w02_1,w03_1,w10_1,w11_1,w12_1,w13_1;

    auto ISSUE = [&](int t,
        short8& aA0, short8& aA1, short8& aB0, short8& aB1,
        short8& w00, short8& w01, short8& w02, short8& w03,
        short8& w10, short8& w11, short8& w12, short8& w13) {
        const int dz = t / 9 - 1, dy = (t / 3) % 3 - 1, dx = t % 3 - 1;
        const unsigned short* At  = Abase + (ptrdiff_t)((dz * P + dy) * P + dx) * 8;
        const unsigned short* At2 = At + (size_t)4 * TOTPADV * 8;
        const unsigned short* Wt  = Wh + (size_t)t * 4096;
        asm volatile("global_load_dwordx4 %0, %1, %2" : "=v"(aA0) : "v"(avF0), "s"(At));
        asm volatile("global_load_dwordx4 %0, %1, %2" : "=v"(aA1) : "v"(avF0), "s"(At2));
        asm volatile("global_load_dwordx4 %0, %1, %2" : "=v"(aB0) : "v"(avF1), "s"(At));
        asm volatile("global_load_dwordx4 %0, %1, %2" : "=v"(aB1) : "v"(avF1), "s"(At2));
        asm volatile("global_load_dwordx4 %0, %1, %2"             : "=v"(w00) : "v"(wvoff), "s"(Wt));
        asm volatile("global_load_dwordx4 %0, %1, %2 offset:256"  : "=v"(w01) : "v"(wvoff), "s"(Wt));
        asm volatile("global_load_dwordx4 %0, %1, %2 offset:512"  : "=v"(w02) : "v"(wvoff), "s"(Wt));
        asm volatile("global_load_dwordx4 %0, %1, %2 offset:768"  : "=v"(w03) : "v"(wvoff), "s"(Wt));
        asm volatile("global_load_dwordx4 %0, %1, %2 offset:1024" : "=v"(w10) : "v"(wvoff), "s"(Wt));
        asm volatile("global_load_dwordx4 %0, %1, %2 offset:1280" : "=v"(w11) : "v"(wvoff), "s"(Wt));
        asm volatile("global_load_dwordx4 %0, %1, %2 offset:1536" : "=v"(w12) : "v"(wvoff), "s"(Wt));
        asm volatile("global_load_dwordx4 %0, %1, %2 offset:1792" : "=v"(w13) : "v"(wvoff), "s"(Wt));
    };
    auto CONS = [&](const short8& aA0, const short8& aA1,
                    const short8& aB0, const short8& aB1,
                    const short8& w00, const short8& w01, const short8& w02, const short8& w03,
                    const short8& w10, const short8& w11, const short8& w12, const short8& w13) {
        c[0][0] = __builtin_amdgcn_mfma_f32_16x16x32_bf16(aA0, w00, c[0][0], 0, 0, 0);
        c[0][1] = __builtin_amdgcn_mfma_f32_16x16x32_bf16(aA0, w01, c[0][1], 0, 0, 0);
        c[0][2] = __builtin_amdgcn_mfma_f32_16x16x32_bf16(aA0, w02, c[0][2], 0, 0, 0);
        c[0][3] = __builtin_amdgcn_mfma_f32_16x16x32_bf16(aA0, w03, c[0][3], 0, 0, 0);
        c[1][0] = __builtin_amdgcn_mfma_f32_16x16x32_bf16(aB0, w00, c[1][0], 0, 0, 0);
        c[1][1] = __builtin_amdgcn_mfma_f32_16x16x32_bf16(aB0, w01, c[1][1], 0, 0, 0);
        c[1][2] = __builtin_amdgcn_mfma_f32_16x16x32_bf16(aB0, w02, c[1][2], 0, 0, 0);
        c[1][3] = __builtin_amdgcn_mfma_f32_16x16x32_bf16(aB0, w03, c[1][3], 0, 0, 0);
        c[0][0] = __builtin_amdgcn_mfma_f32_16x16x32_bf16(aA1, w10, c[0][0], 0, 0, 0);
        c[0][1] = __builtin_amdgcn_mfma_f32_16x16x32_bf16(aA1, w11, c[0][1], 0, 0, 0);
        c[0][2] = __builtin_amdgcn_mfma_f32_16x16x32_bf16(aA1, w12, c[0][2], 0, 0, 0);
        c[0][3] = __builtin_amdgcn_mfma_f32_16x16x32_bf16(aA1, w13, c[0][3], 0, 0, 0);
        c[1][0] = __builtin_amdgcn_mfma_f32_16x16x32_bf16(aB1, w10, c[1][0], 0, 0, 0);
        c[1][1] = __builtin_amdgcn_mfma_f32_16x16x32_bf16(aB1, w11, c[1][1], 0, 0, 0);
        c[1][2] = __builtin_amdgcn_mfma_f32_16x16x32_bf16(aB1, w12, c[1][2], 0, 0, 0);
        c[1][3] = __builtin_amdgcn_mfma_f32_16x16x32_bf16(aB1, w13, c[1][3], 0, 0, 0);
    };

    #define SL0 aA0_0,aA1_0,aB0_0,aB1_0,w00_0,w01_0,w02_0,w03_0,w10_0,w11_0,w12_0,w13_0
    #define SL1 aA0_1,aA1_1,aB0_1,aB1_1,w00_1,w01_1,w02_1,w03_1,w10_1,w11_1,w12_1,w13_1
    #define WAITV(N) do { asm volatile("s_waitcnt vmcnt(" #N ")" ::: "memory"); \
                          __builtin_amdgcn_sched_barrier(0); } while (0)
    #define STEP2(ta, tb) \
        WAITV(12); CONS(SL0); ISSUE(ta, SL0); \
        WAITV(12); CONS(SL1); ISSUE(tb, SL1);

    ISSUE(0, SL0); ISSUE(1, SL1);
    STEP2(2, 3)   STEP2(4, 5)   STEP2(6, 7)   STEP2(8, 9)
    STEP2(10, 11) STEP2(12, 13) STEP2(14, 15) STEP2(16, 17)
    STEP2(18, 19) STEP2(20, 21) STEP2(22, 23) STEP2(24, 25)
    WAITV(12); CONS(SL0); ISSUE(26, SL0);
    WAITV(12); CONS(SL1);
    WAITV(0);  CONS(SL0);

    #undef SL0
    #undef SL1
    #undef WAITV
    #undef STEP2

    const float* bptr = head ? b_reg : b_cls;

    if constexpr (!FINAL) {
        if (wvalid) {
            #pragma unroll
            for (int cg = 0; cg < 4; ++cg) {
                const int cout = cg * 16 + row;
                const float bias = bptr[cout];
                float s1 = 0.f, s2 = 0.f;
                #pragma unroll
                for (int i = 0; i < 2; ++i) {
                    #pragma unroll
                    for (int r = 0; r < 4; ++r) {
                        const float val = c[i][cg][r] + bias;
                        const int vg = wbase + i * 16 + kg * 4 + r;
                        raw[((size_t)(head * 8 + (cout >> 3)) * TOTVOX + vg) * 8
                            + (cout & 7)] = f2b(val);
                        s1 += val; s2 += val * val;
                    }
                }
                s1 += __shfl_xor(s1, 16, 64); s1 += __shfl_xor(s1, 32, 64);
                s2 += __shfl_xor(s2, 16, 64); s2 += __shfl_xor(s2, 32, 64);
                if (lane < 16) {
                    float* st = stats + ((head * 4 + lvl) * 64 + cg * 16 + lane) * 2;
                    atomicAdd(st + 0, s1);
                    atomicAdd(st + 1, s2);
                }
            }
        }
    } else {
        if (wvalid) {
            const int OUT = head ? 54 : 18;
            float* ob = dout + (head ? CLS_TOTAL : 0);
            #pragma unroll
            for (int cg = 0; cg < 4; ++cg) {
                const int cout = cg * 16 + row;
                if (cout < OUT) {
                    const float bias = bptr[cout];
                    #pragma unroll
                    for (int i = 0; i < 2; ++i) {
                        #pragma unroll
                        for (int r = 0; r < 4; ++r) {
                            const int vg = wbase + i * 16 + kg * 4 + r;
                            ob[(size_t)vg * OUT + cout] = c[i][cg][r] + bias;
                        }
                    }
                }
            }
        }
    }
}

// ---------------------------------------------------------------------------
// InstanceNorm + PReLU: raw [head][slice][vox][8] -> padded slice-major dst.
// Grid (1170, 2). Per thread: one (slice, vox) pair. Strict src->dst.
// ---------------------------------------------------------------------------
__global__ __launch_bounds__(256) void norm_kernel(
    const unsigned short* __restrict__ raw, const float* __restrict__ stats,
    const float* __restrict__ a_cls, const float* __restrict__ a_reg,
    const int layer, unsigned short* __restrict__ pad)
{
    const int tid  = threadIdx.x;
    const int head = blockIdx.y;
    const int b    = xcdswz1170(blockIdx.x);

    int lvl, ls, S, P, loff, cvol, base;
    blkdec32(b, lvl, ls, S, P, loff, cvol, base);

    const int vg = base + (tid >> 3);            // global voxel
    const int v  = vg - loff;
    const int s  = tid & 7;                      // slice
    const int x = v & (S - 1), y = (v >> ls) & (S - 1), z = v >> (2 * ls);
    const int pb = ((z + 1) * P + (y + 1)) * P + (x + 1);

    const float inv_n = 1.0f / (float)(1 << (3 * ls));
    const float alpha = (head ? a_reg : a_cls)[layer];
    const float* st = stats + (size_t)((head * 4 + lvl) * 64) * 2;

    const ushort8 u = *reinterpret_cast<const ushort8*>(
        raw + ((size_t)(head * 8 + s) * TOTVOX + vg) * 8);
    ushort8 o;
    #pragma unroll
    for (int j = 0; j < 8; ++j) {
        const int cch = s * 8 + j;
        const float m = st[cch * 2] * inv_n;
        float var = st[cch * 2 + 1] * inv_n - m * m;
        const float rs = rsqrtf(fmaxf(var, 0.0f) + 1e-5f);
        float val = (b2f(u[j]) - m) * rs;
        val = (val >= 0.0f) ? val : alpha * val;
        o[j] = f2b(val);
    }
    *reinterpret_cast<ushort8*>(pad + (size_t)head * PAD_HSTRIDE_E
                                    + ((size_t)s * TOTPADV + cvol + pb) * 8) = o;
}

// ---------------------------------------------------------------------------
extern "C" void kernel_launch(void* const* d_in, const int* in_sizes, int n_in,
                              void* d_out, int out_size, void* d_ws, size_t ws_size,
                              hipStream_t stream)
{
    const float* p0      = (const float*)d_in[0];
    const float* p1      = (const float*)d_in[1];
    const float* p2      = (const float*)d_in[2];
    const float* p3      = (const float*)d_in[3];
    const float* cls_w1  = (const float*)d_in[4];
    const float* cls_b1  = (const float*)d_in[5];
    const float* cls_w234= (const float*)d_in[6];
    const float* cls_b234= (const float*)d_in[7];
    const float* cls_a   = (const float*)d_in[8];
    const float* cls_wf  = (const float*)d_in[9];
    const float* cls_bf  = (const float*)d_in[10];
    const float* reg_w1  = (const float*)d_in[11];
    const float* reg_b1  = (const float*)d_in[12];
    const float* reg_w234= (const float*)d_in[13];
    const float* reg_b234= (const float*)d_in[14];
    const float* reg_a   = (const float*)d_in[15];
    const float* reg_wf  = (const float*)d_in[16];
    const float* reg_bf  = (const float*)d_in[17];

    char* ws = (char*)d_ws;
    float*          stats  = (float*)ws;                         // 16,384 B
    unsigned short* padIn0 = (unsigned short*)(ws + 16384);      // 5,933,056 B
    unsigned short* padA   = (unsigned short*)(ws + 5949440);    // 11,866,112 B
    unsigned short* padB   = (unsigned short*)(ws + 17815552);   // 11,866,112 B
    unsigned short* raw    = (unsigned short*)(ws + 29681664);   // 9,584,640 B
    unsigned short* wcvt   = (unsigned short*)(ws + 39266304);   // 2,211,840 B

    // zero stats + all padded activation buffers (pads must be 0 every call);
    // raw and wcvt are fully written before any read each call.
    hipMemsetAsync(ws, 0, 29681664, stream);

    wconv_kernel<<<4320, 256, 0, stream>>>(
        cls_w1, reg_w1, cls_w234, reg_w234, cls_wf, reg_wf, wcvt);
    inconv_kernel<<<1170, 256, 0, stream>>>(p0, p1, p2, p3, padIn0);

    const dim3 cgrid(293, 2);
    const dim3 ngrid(1170, 2);

    // layer 0: padIn0 (shared heads: stride 0) -> raw -> padA
    conv_mfma_kernel<false><<<cgrid, 256, 0, stream>>>(
        padIn0, 0, wcvt, cls_b1, reg_b1, stats, raw, nullptr);
    norm_kernel<<<ngrid, 256, 0, stream>>>(raw, stats, cls_a, reg_a, 0, padA);

    // layers 1..3: padA -> raw -> padB -> raw -> padA -> raw -> padB
    unsigned short* srcs[3] = { padA, padB, padA };
    unsigned short* dsts[3] = { padB, padA, padB };
    for (int l = 0; l < 3; ++l) {
        conv_mfma_kernel<false><<<cgrid, 256, 0, stream>>>(
            srcs[l], PAD_HSTRIDE_E, wcvt + (size_t)(l + 1) * WLAYER_E,
            cls_b234 + l * 64, reg_b234 + l * 64,
            stats + (l + 1) * 1024, raw, nullptr);
        norm_kernel<<<ngrid, 256, 0, stream>>>(
            raw, stats + (l + 1) * 1024, cls_a, reg_a, l + 1, dsts[l]);
    }

    // final conv: padB -> d_out (channel-last fp32, cls then reg)
    conv_mfma_kernel<true><<<cgrid, 256, 0, stream>>>(
        padB, PAD_HSTRIDE_E, wcvt + 4 * WLAYER_E,
        cls_bf, reg_bf, nullptr, nullptr, (float*)d_out);
}

// Round 12
// 526.671 us; speedup vs baseline: 1.1754x; 1.1754x over previous
//
#include <hip/hip_runtime.h>

// RetinaNet 3D head via bf16 MFMA implicit GEMM.
// 2 heads x 4 levels (S=32,16,8,4; vox 32768,4096,512,64; total 37440).
//
// Layouts (r10-proven full-line):
//   activations: [head][slice(8)][pvox][8ch]  (16B per (slice,vox))
//   weights:     [layer][head][tap][slice(8)][cout(64)][8ch]
// r12 core: block (32vox x 64cout, 4 waves of 32vox x 16cout — r10 tiling)
// stages per tap A(4KB)+W(8KB) into DOUBLE-BUFFERED LDS via 3 global_load_lds
// per wave; fragments are LDS reads shared by all 4 waves (kills the 4x A
// redundancy; per-CU global bytes halved). Sync = 2 raw s_barriers per tap
// with COUNTED vmcnt(3) (one stage in flight; no full drain) + lgkmcnt(0)
// before the 2nd barrier (reads serviced before anyone's next-tap stage
// writes the other... same buffer two taps later).  Strict
// producer->consumer dataflow across kernels (replay-safe).

typedef __attribute__((ext_vector_type(8)))  short short8;
typedef __attribute__((ext_vector_type(8)))  unsigned short ushort8;
typedef __attribute__((ext_vector_type(4)))  float f32x4;

static constexpr int TOTVOX    = 37440;
static constexpr int CLS_TOTAL = 673920;                  // 18 * 37440
static constexpr int TOTPADV   = 46352;                   // 39304+5832+1000+216
static constexpr size_t PAD_HSTRIDE_E = (size_t)TOTPADV * 64;  // elems per head
static constexpr size_t WLAYER_E = 2u * 27 * 4096;        // elems per layer (2 heads)

__device__ __forceinline__ unsigned short f2b(float x) {
    unsigned int u = __float_as_uint(x);
    u += 0x7FFFu + ((u >> 16) & 1u);
    return (unsigned short)(u >> 16);
}
__device__ __forceinline__ float b2f(unsigned short h) {
    return __uint_as_float(((unsigned)h) << 16);
}

// bijective XCD swizzle for nwg=1170 (q=146, r=2), m204 form
__device__ __forceinline__ int xcdswz1170(int orig) {
    const int xcd = orig & 7;
    return (xcd < 2 ? xcd * 147 : 294 + (xcd - 2) * 146) + (orig >> 3);
}

// 32-voxel blocks: b in [0,1170): l0:1024, l1:128, l2:16, l3:2
__device__ __forceinline__ void blkdec32(int b, int& lvl, int& ls, int& S, int& P,
                                         int& loff, int& cvol, int& base)
{
    if (b < 1024)      { lvl = 0; base = b * 32; }
    else if (b < 1152) { lvl = 1; base = 32768 + (b - 1024) * 32; }
    else if (b < 1168) { lvl = 2; base = 36864 + (b - 1152) * 32; }
    else               { lvl = 3; base = 37376 + (b - 1168) * 32; }
    ls = 5 - lvl; S = 1 << ls; P = S + 2;
    loff = (lvl == 0) ? 0 : (lvl == 1) ? 32768 : (lvl == 2) ? 36864 : 37376;
    cvol = (lvl == 0) ? 0 : (lvl == 1) ? 39304 : (lvl == 2) ? 45136 : 46136;
}

__device__ __forceinline__ void voxdec(int vox, int& lvl, int& ls, int& loff,
                                       int& cvol, int& pbase)
{
    if (vox < 32768)      lvl = 0;
    else if (vox < 36864) lvl = 1;
    else if (vox < 37376) lvl = 2;
    else                  lvl = 3;
    ls = 5 - lvl;
    const int S = 1 << ls, P = S + 2;
    loff = (lvl == 0) ? 0 : (lvl == 1) ? 32768 : (lvl == 2) ? 36864 : 37376;
    cvol = (lvl == 0) ? 0 : (lvl == 1) ? 39304 : (lvl == 2) ? 45136 : 46136;
    const int v = vox - loff;
    const int x = v & (S - 1), y = (v >> ls) & (S - 1), z = v >> (2 * ls);
    pbase = ((z + 1) * P + (y + 1)) * P + (x + 1);
}

__device__ __forceinline__ void gl16(const unsigned short* g, void* l) {
    __builtin_amdgcn_global_load_lds(
        (const __attribute__((address_space(1))) void*)g,
        (__attribute__((address_space(3))) void*)l, 16, 0, 0);
}

// ---------------------------------------------------------------------------
// Weight conversion -> bf16 [layer][head][tap][slice(8)][cout(64)][8ch].
// ---------------------------------------------------------------------------
__global__ __launch_bounds__(256) void wconv_kernel(
    const float* __restrict__ cls_w1, const float* __restrict__ reg_w1,
    const float* __restrict__ cls_w234, const float* __restrict__ reg_w234,
    const float* __restrict__ cls_wf, const float* __restrict__ reg_wf,
    unsigned short* __restrict__ dst)
{
    const int id = blockIdx.x * 256 + (int)threadIdx.x;   // < 1,105,920
    const int s  = id / 221184;
    const int r  = id - s * 221184;
    const int head = r / 110592;
    const int r2 = r - head * 110592;
    const int t  = r2 >> 12;
    const int q  = r2 & 4095;
    const int slice = q >> 9;
    const int co = (q >> 3) & 63;
    const int ci = slice * 8 + (q & 7);

    float val = 0.0f;
    if (s == 0) {
        if (ci < 36) {
            const float* w = head ? reg_w1 : cls_w1;      // [64][36][27]
            val = w[(co * 36 + ci) * 27 + t];
        }
    } else if (s <= 3) {
        const float* w = (head ? reg_w234 : cls_w234) + (size_t)(s - 1) * 110592;
        val = w[(co * 64 + ci) * 27 + t];                 // [64][64][27]
    } else {
        const int OUT = head ? 54 : 18;
        if (co < OUT) {
            const float* w = head ? reg_wf : cls_wf;      // [OUT][64][27]
            val = w[(co * 64 + ci) * 27 + t];
        }
    }
    dst[id] = f2b(val);
}

// ---------------------------------------------------------------------------
// Input conversion: p0..p3 fp32 [36][nvox] -> padded slice-major bf16.
// ---------------------------------------------------------------------------
__global__ __launch_bounds__(256) void inconv_kernel(
    const float* __restrict__ p0, const float* __restrict__ p1,
    const float* __restrict__ p2, const float* __restrict__ p3,
    unsigned short* __restrict__ padin)
{
    const int id = blockIdx.x * 256 + (int)threadIdx.x;   // < 299,520
    const int s   = id / 37440;
    const int vox = id - s * 37440;

    int lvl, ls, loff, cvol, pbase;
    voxdec(vox, lvl, ls, loff, cvol, pbase);
    const int nvox = 1 << (3 * ls);
    const int lvox = vox - loff;
    const float* src = (lvl == 0) ? p0 : (lvl == 1) ? p1 : (lvl == 2) ? p2 : p3;

    ushort8 o;
    #pragma unroll
    for (int j = 0; j < 8; ++j) {
        const int c = s * 8 + j;
        o[j] = (c < 36) ? f2b(src[c * nvox + lvox]) : (unsigned short)0;
    }
    *reinterpret_cast<ushort8*>(padin + ((size_t)s * TOTPADV + cvol + pbase) * 8) = o;
}

// ---------------------------------------------------------------------------
// Conv layer: implicit GEMM with LDS-staged tiles.
// Grid (1170, 2 heads), 256 thr = 4 waves; block 32vox x 64cout;
// wave 32vox x 16cout. Per tap: 3 global_load_lds per wave (A 4KB + W 8KB
// block-wide), 2 barriers, counted vmcnt(3); 6 LDS frag reads; 4 MFMAs.
// ---------------------------------------------------------------------------
template<bool FINAL>
__global__ __launch_bounds__(256) void conv_mfma_kernel(
    const unsigned short* __restrict__ A, const size_t a_head_stride_e,
    const unsigned short* __restrict__ W,
    const float* __restrict__ b_cls, const float* __restrict__ b_reg,
    float* __restrict__ stats, unsigned short* __restrict__ raw,
    float* __restrict__ dout)
{
    __shared__ short8 Albuf[2][256];   //  8 KB: [slice(8)][vox(32)]
    __shared__ short8 Wlbuf[2][512];   // 16 KB: [slice(8)][cout(64)]

    const int tid  = threadIdx.x;
    const int head = blockIdx.y;
    const int b    = xcdswz1170(blockIdx.x);

    int lvl, ls, S, P, loff, cvol, base;
    blkdec32(b, lvl, ls, S, P, loff, cvol, base);

    const int lane = tid & 63, wv = tid >> 6;
    const int row = lane & 15, kg = lane >> 4;
    const int cout = wv * 16 + row;

    const unsigned short* Abase = A + (size_t)head * a_head_stride_e;
    const unsigned short* Wh = W + (size_t)head * (27 * 4096);

    // per-lane A-stage source base (slice = wv*2 + lane>>5, vox = lane&31)
    const unsigned short* aSrcBase;
    {
        const int sl = wv * 2 + (lane >> 5);
        const int v  = lane & 31;
        const int iv = (base - loff) + v;
        const int x = iv & (S - 1), y = (iv >> ls) & (S - 1), z = iv >> (2 * ls);
        const int pb = ((z + 1) * P + (y + 1)) * P + (x + 1);
        aSrcBase = Abase + ((size_t)sl * TOTPADV + cvol + pb) * 8;
    }
    const int lane8 = lane * 8;   // 16B per lane, in ushort units

    f32x4 acc0 = {0.f,0.f,0.f,0.f}, acc1 = acc0;

    auto STAGE = [&](int t, int bs) {
        const int dz = t / 9 - 1, dy = (t / 3) % 3 - 1, dx = t % 3 - 1;
        const int tapoff = ((dz * P + dy) * P + dx) * 8;   // ushort units
        gl16(aSrcBase + tapoff, &Albuf[bs][wv * 64]);
        const unsigned short* Wt = Wh + (size_t)t * 4096;
        gl16(Wt + wv * 512 + lane8,        &Wlbuf[bs][wv * 64]);
        gl16(Wt + 2048 + wv * 512 + lane8, &Wlbuf[bs][256 + wv * 64]);
    };

    #define FENCE asm volatile("" ::: "memory")
    #define BARRIER do { FENCE; __builtin_amdgcn_s_barrier(); FENCE; } while (0)
    #define WAITV3 do { asm volatile("s_waitcnt vmcnt(3)" ::: "memory"); \
                        __builtin_amdgcn_sched_barrier(0); } while (0)
    #define WAITV0 do { asm volatile("s_waitcnt vmcnt(0)" ::: "memory"); \
                        __builtin_amdgcn_sched_barrier(0); } while (0)
    #define LGKM0  asm volatile("s_waitcnt lgkmcnt(0)" ::: "memory")

    STAGE(0, 0);
    for (int t = 0; t < 27; ++t) {
        const int bs = t & 1;
        if (t < 26) { STAGE(t + 1, bs ^ 1); WAITV3; }
        else        { WAITV0; }
        BARRIER;
        const short8 a00 = Albuf[bs][kg * 32 + row];
        const short8 a10 = Albuf[bs][kg * 32 + row + 16];
        const short8 a01 = Albuf[bs][(kg + 4) * 32 + row];
        const short8 a11 = Albuf[bs][(kg + 4) * 32 + row + 16];
        const short8 w0  = Wlbuf[bs][kg * 64 + cout];
        const short8 w1  = Wlbuf[bs][256 + kg * 64 + cout];
        acc0 = __builtin_amdgcn_mfma_f32_16x16x32_bf16(a00, w0, acc0, 0, 0, 0);
        acc1 = __builtin_amdgcn_mfma_f32_16x16x32_bf16(a10, w0, acc1, 0, 0, 0);
        acc0 = __builtin_amdgcn_mfma_f32_16x16x32_bf16(a01, w1, acc0, 0, 0, 0);
        acc1 = __builtin_amdgcn_mfma_f32_16x16x32_bf16(a11, w1, acc1, 0, 0, 0);
        LGKM0;
        BARRIER;
    }

    #undef FENCE
    #undef BARRIER
    #undef WAITV3
    #undef WAITV0
    #undef LGKM0

    const float bias = (head ? b_reg : b_cls)[cout];

    if constexpr (!FINAL) {
        unsigned short* rp = raw;
        float s1 = 0.f, s2 = 0.f;
        #pragma unroll
        for (int i = 0; i < 2; ++i) {
            const f32x4 a = i ? acc1 : acc0;
            #pragma unroll
            for (int r = 0; r < 4; ++r) {
                const float val = a[r] + bias;
                const int vg = base + i * 16 + kg * 4 + r;   // global voxel id
                rp[((size_t)(head * 8 + (cout >> 3)) * TOTVOX + vg) * 8
                   + (cout & 7)] = f2b(val);
                s1 += val; s2 += val * val;
            }
        }
        s1 += __shfl_xor(s1, 16, 64); s1 += __shfl_xor(s1, 32, 64);
        s2 += __shfl_xor(s2, 16, 64); s2 += __shfl_xor(s2, 32, 64);
        if (lane < 16) {
            float* st = stats + ((head * 4 + lvl) * 64 + wv * 16 + lane) * 2;
            atomicAdd(st + 0, s1);
            atomicAdd(st + 1, s2);
        }
    } else {
        const int OUT = head ? 54 : 18;
        if (cout < OUT) {
            float* ob = dout + (head ? CLS_TOTAL : 0);
            #pragma unroll
            for (int i = 0; i < 2; ++i) {
                const f32x4 a = i ? acc1 : acc0;
                #pragma unroll
                for (int r = 0; r < 4; ++r) {
                    const int vg = base + i * 16 + kg * 4 + r;
                    ob[(size_t)vg * OUT + cout] = a[r] + bias;
                }
            }
        }
    }
}

// ---------------------------------------------------------------------------
// InstanceNorm + PReLU: raw [head][slice][vox][8] -> padded slice-major dst.
// Grid (1170, 2). Per thread: one (slice, vox) pair. Strict src->dst.
// ---------------------------------------------------------------------------
__global__ __launch_bounds__(256) void norm_kernel(
    const unsigned short* __restrict__ raw, const float* __restrict__ stats,
    const float* __restrict__ a_cls, const float* __restrict__ a_reg,
    const int layer, unsigned short* __restrict__ pad)
{
    const int tid  = threadIdx.x;
    const int head = blockIdx.y;
    const int b    = xcdswz1170(blockIdx.x);

    int lvl, ls, S, P, loff, cvol, base;
    blkdec32(b, lvl, ls, S, P, loff, cvol, base);

    const int vg = base + (tid >> 3);            // global voxel
    const int v  = vg - loff;
    const int s  = tid & 7;                      // slice
    const int x = v & (S - 1), y = (v >> ls) & (S - 1), z = v >> (2 * ls);
    const int pb = ((z + 1) * P + (y + 1)) * P + (x + 1);

    const float inv_n = 1.0f / (float)(1 << (3 * ls));
    const float alpha = (head ? a_reg : a_cls)[layer];
    const float* st = stats + (size_t)((head * 4 + lvl) * 64) * 2;

    const ushort8 u = *reinterpret_cast<const ushort8*>(
        raw + ((size_t)(head * 8 + s) * TOTVOX + vg) * 8);
    ushort8 o;
    #pragma unroll
    for (int j = 0; j < 8; ++j) {
        const int cch = s * 8 + j;
        const float m = st[cch * 2] * inv_n;
        float var = st[cch * 2 + 1] * inv_n - m * m;
        const float rs = rsqrtf(fmaxf(var, 0.0f) + 1e-5f);
        float val = (b2f(u[j]) - m) * rs;
        val = (val >= 0.0f) ? val : alpha * val;
        o[j] = f2b(val);
    }
    *reinterpret_cast<ushort8*>(pad + (size_t)head * PAD_HSTRIDE_E
                                    + ((size_t)s * TOTPADV + cvol + pb) * 8) = o;
}

// ---------------------------------------------------------------------------
extern "C" void kernel_launch(void* const* d_in, const int* in_sizes, int n_in,
                              void* d_out, int out_size, void* d_ws, size_t ws_size,
                              hipStream_t stream)
{
    const float* p0      = (const float*)d_in[0];
    const float* p1      = (const float*)d_in[1];
    const float* p2      = (const float*)d_in[2];
    const float* p3      = (const float*)d_in[3];
    const float* cls_w1  = (const float*)d_in[4];
    const float* cls_b1  = (const float*)d_in[5];
    const float* cls_w234= (const float*)d_in[6];
    const float* cls_b234= (const float*)d_in[7];
    const float* cls_a   = (const float*)d_in[8];
    const float* cls_wf  = (const float*)d_in[9];
    const float* cls_bf  = (const float*)d_in[10];
    const float* reg_w1  = (const float*)d_in[11];
    const float* reg_b1  = (const float*)d_in[12];
    const float* reg_w234= (const float*)d_in[13];
    const float* reg_b234= (const float*)d_in[14];
    const float* reg_a   = (const float*)d_in[15];
    const float* reg_wf  = (const float*)d_in[16];
    const float* reg_bf  = (const float*)d_in[17];

    char* ws = (char*)d_ws;
    float*          stats  = (float*)ws;                         // 16,384 B
    unsigned short* padIn0 = (unsigned short*)(ws + 16384);      // 5,933,056 B
    unsigned short* padA   = (unsigned short*)(ws + 5949440);    // 11,866,112 B
    unsigned short* padB   = (unsigned short*)(ws + 17815552);   // 11,866,112 B
    unsigned short* raw    = (unsigned short*)(ws + 29681664);   // 9,584,640 B
    unsigned short* wcvt   = (unsigned short*)(ws + 39266304);   // 2,211,840 B

    // zero stats + all padded activation buffers (pads must be 0 every call);
    // raw and wcvt are fully written before any read each call.
    hipMemsetAsync(ws, 0, 29681664, stream);

    wconv_kernel<<<4320, 256, 0, stream>>>(
        cls_w1, reg_w1, cls_w234, reg_w234, cls_wf, reg_wf, wcvt);
    inconv_kernel<<<1170, 256, 0, stream>>>(p0, p1, p2, p3, padIn0);

    const dim3 cgrid(1170, 2);

    // layer 0: padIn0 (shared heads: stride 0) -> raw -> padA
    conv_mfma_kernel<false><<<cgrid, 256, 0, stream>>>(
        padIn0, 0, wcvt, cls_b1, reg_b1, stats, raw, nullptr);
    norm_kernel<<<cgrid, 256, 0, stream>>>(raw, stats, cls_a, reg_a, 0, padA);

    // layers 1..3: padA -> raw -> padB -> raw -> padA -> raw -> padB
    unsigned short* srcs[3] = { padA, padB, padA };
    unsigned short* dsts[3] = { padB, padA, padB };
    for (int l = 0; l < 3; ++l) {
        conv_mfma_kernel<false><<<cgrid, 256, 0, stream>>>(
            srcs[l], PAD_HSTRIDE_E, wcvt + (size_t)(l + 1) * WLAYER_E,
            cls_b234 + l * 64, reg_b234 + l * 64,
            stats + (l + 1) * 1024, raw, nullptr);
        norm_kernel<<<cgrid, 256, 0, stream>>>(
            raw, stats + (l + 1) * 1024, cls_a, reg_a, l + 1, dsts[l]);
    }

    // final conv: padB -> d_out (channel-last fp32, cls then reg)
    conv_mfma_kernel<true><<<cgrid, 256, 0, stream>>>(
        padB, PAD_HSTRIDE_E, wcvt + 4 * WLAYER_E,
        cls_bf, reg_bf, nullptr, nullptr, (float*)d_out);
}